// Round 1
// baseline (1178.226 us; speedup 1.0000x reference)
//
#include <hip/hip_runtime.h>

typedef short bf16x8 __attribute__((ext_vector_type(8)));
typedef float floatx4 __attribute__((ext_vector_type(4)));
typedef unsigned short u16x4 __attribute__((ext_vector_type(4)));
typedef unsigned short u16x8 __attribute__((ext_vector_type(8)));

__device__ __forceinline__ unsigned short f2bf(float f) {
  union { float f; unsigned int u; } v;
  v.f = f;
  unsigned int u = v.u + (0x7FFFu + ((v.u >> 16) & 1u));  // round-to-nearest-even
  return (unsigned short)(u >> 16);
}

// ---------------------------------------------------------------------------
// Pack all four weight matrices to bf16 in MFMA-B-fragment-friendly layout:
//   Wf[g][n][j] = W[g*8 + j][n]   (g = k/8, j = k%8)
// so a lane's B-fragment (8 bf16 along k) is 16 contiguous bytes.
// Regions: msg_W1 [192x128] -> 24576, msg_W2 [128x64] -> 8192,
//          node_W1 [128x128] -> 16384, node_W2 [128x64] -> 8192.  Total 57344.
// ---------------------------------------------------------------------------
__global__ __launch_bounds__(256) void prep_weights(
    const float* __restrict__ mW1, const float* __restrict__ mW2,
    const float* __restrict__ nW1, const float* __restrict__ nW2,
    unsigned short* __restrict__ W1f, unsigned short* __restrict__ W2f,
    unsigned short* __restrict__ NW1f, unsigned short* __restrict__ NW2f) {
  int idx = blockIdx.x * 256 + threadIdx.x;
  if (idx < 24576) {
    int j = idx & 7, n = (idx >> 3) & 127, g = idx >> 10;
    W1f[idx] = f2bf(mW1[(g * 8 + j) * 128 + n]);
  } else if (idx < 32768) {
    int t = idx - 24576;
    int j = t & 7, n = (t >> 3) & 63, g = t >> 9;
    W2f[t] = f2bf(mW2[(g * 8 + j) * 64 + n]);
  } else if (idx < 49152) {
    int t = idx - 32768;
    int j = t & 7, n = (t >> 3) & 127, g = t >> 10;
    NW1f[t] = f2bf(nW1[(g * 8 + j) * 128 + n]);
  } else if (idx < 57344) {
    int t = idx - 49152;
    int j = t & 7, n = (t >> 3) & 63, g = t >> 9;
    NW2f[t] = f2bf(nW2[(g * 8 + j) * 64 + n]);
  }
}

// ---------------------------------------------------------------------------
// Edge kernel: per block of 128 edges,
//   X[128x192] = concat(nodes[snd], nodes[rcv], edges)   (bf16, K-sliced)
//   H = relu(X @ msg_W1 + b1)        GEMM1: K=192, N=128
//   M = relu(H @ msg_W2 + b2)        GEMM2: K=128, N=64
//   atomicAdd M into agg[rcv]        (agg = d_out, pre-zeroed)
// 4 waves in 2x2 grid; 4x4 / 4x2 register tiles of mfma_f32_16x16x32_bf16.
// ---------------------------------------------------------------------------
__global__ __launch_bounds__(256) void edge_kernel(
    const float* __restrict__ nodes, const float* __restrict__ edges,
    const int* __restrict__ senders, const int* __restrict__ receivers,
    const unsigned short* __restrict__ W1f, const unsigned short* __restrict__ W2f,
    const float* __restrict__ b1, const float* __restrict__ b2,
    float* agg, int E) {
  __shared__ int snd[128];
  __shared__ int rcv[128];
  __shared__ unsigned short Xs[128 * 40];   // 32-wide K slice, pad to 40 (bank-spread)
  __shared__ unsigned short Ws[4096];       // one W K-slice (fragment layout)
  __shared__ unsigned short Hl[128 * 136];  // hidden, pad 128->136

  const int tid = threadIdx.x;
  const int e0 = blockIdx.x * 128;
  const int w = tid >> 6, lane = tid & 63;
  const int col = lane & 15, quad = lane >> 4;
  const int wm = w & 1, wn = w >> 1;

  if (tid < 128) {
    int ge = e0 + tid;
    snd[tid] = (ge < E) ? senders[ge] : 0;
    rcv[tid] = (ge < E) ? receivers[ge] : 0;
  }

  floatx4 z4 = {0.f, 0.f, 0.f, 0.f};
  floatx4 acc1[4][4];
#pragma unroll
  for (int mt = 0; mt < 4; ++mt)
#pragma unroll
    for (int nt = 0; nt < 4; ++nt) acc1[mt][nt] = z4;

  for (int ks = 0; ks < 6; ++ks) {
    __syncthreads();  // prev slice consumed (and snd/rcv ready on iter 0)
    // stage X K-slice: 128 edges x 32 features, fp32 -> bf16
    for (int t = tid; t < 1024; t += 256) {
      int e = t >> 3, c = t & 7;
      float4 v;
      if (e0 + e < E) {
        int off = (ks & 1) * 32 + c * 4;
        const float* src;
        if (ks < 2)      src = nodes + (size_t)snd[e] * 64 + off;
        else if (ks < 4) src = nodes + (size_t)rcv[e] * 64 + off;
        else             src = edges + (size_t)(e0 + e) * 64 + off;
        v = *(const float4*)src;
      } else {
        v = make_float4(0.f, 0.f, 0.f, 0.f);
      }
      u16x4 h;
      h.x = f2bf(v.x); h.y = f2bf(v.y); h.z = f2bf(v.z); h.w = f2bf(v.w);
      *(u16x4*)&Xs[e * 40 + c * 4] = h;
    }
    // stage W1 K-slice: 4096 shorts, contiguous in packed layout
    *(u16x8*)&Ws[tid * 8] = *(const u16x8*)&W1f[ks * 4096 + tid * 8];
    *(u16x8*)&Ws[(tid + 256) * 8] = *(const u16x8*)&W1f[ks * 4096 + (tid + 256) * 8];
    __syncthreads();

    bf16x8 a[4], b[4];
#pragma unroll
    for (int mt = 0; mt < 4; ++mt)
      a[mt] = *(const bf16x8*)&Xs[(wm * 64 + mt * 16 + col) * 40 + quad * 8];
#pragma unroll
    for (int nt = 0; nt < 4; ++nt)
      b[nt] = *(const bf16x8*)&Ws[(quad * 128 + wn * 64 + nt * 16 + col) * 8];
#pragma unroll
    for (int mt = 0; mt < 4; ++mt)
#pragma unroll
      for (int nt = 0; nt < 4; ++nt)
        acc1[mt][nt] = __builtin_amdgcn_mfma_f32_16x16x32_bf16(a[mt], b[nt], acc1[mt][nt], 0, 0, 0);
  }

  // bias + ReLU -> Hl (bf16), C-layout -> A-layout via LDS
#pragma unroll
  for (int nt = 0; nt < 4; ++nt) {
    float bias = b1[wn * 64 + nt * 16 + col];
#pragma unroll
    for (int mt = 0; mt < 4; ++mt)
#pragma unroll
      for (int r = 0; r < 4; ++r) {
        float v = acc1[mt][nt][r] + bias;
        v = v > 0.f ? v : 0.f;
        Hl[(wm * 64 + mt * 16 + quad * 4 + r) * 136 + wn * 64 + nt * 16 + col] = f2bf(v);
      }
  }

  floatx4 acc2[4][2];
#pragma unroll
  for (int mt = 0; mt < 4; ++mt) { acc2[mt][0] = z4; acc2[mt][1] = z4; }

  for (int ks = 0; ks < 4; ++ks) {
    __syncthreads();  // Ws consumers done; on iter 0 also fences Hl writes
    *(u16x8*)&Ws[tid * 8] = *(const u16x8*)&W2f[ks * 2048 + tid * 8];
    __syncthreads();
    bf16x8 a[4], b[2];
#pragma unroll
    for (int mt = 0; mt < 4; ++mt)
      a[mt] = *(const bf16x8*)&Hl[(wm * 64 + mt * 16 + col) * 136 + ks * 32 + quad * 8];
#pragma unroll
    for (int nt = 0; nt < 2; ++nt)
      b[nt] = *(const bf16x8*)&Ws[(quad * 64 + wn * 32 + nt * 16 + col) * 8];
#pragma unroll
    for (int mt = 0; mt < 4; ++mt)
#pragma unroll
      for (int nt = 0; nt < 2; ++nt)
        acc2[mt][nt] = __builtin_amdgcn_mfma_f32_16x16x32_bf16(a[mt], b[nt], acc2[mt][nt], 0, 0, 0);
  }

  float bs0 = b2[wn * 32 + col];
  float bs1 = b2[wn * 32 + 16 + col];
#pragma unroll
  for (int mt = 0; mt < 4; ++mt)
#pragma unroll
    for (int r = 0; r < 4; ++r) {
      int i = wm * 64 + mt * 16 + quad * 4 + r;
      if (e0 + i < E) {
        int rv = rcv[i];
        float v0 = acc2[mt][0][r] + bs0; v0 = v0 > 0.f ? v0 : 0.f;
        float v1 = acc2[mt][1][r] + bs1; v1 = v1 > 0.f ? v1 : 0.f;
        atomicAdd(&agg[(size_t)rv * 64 + wn * 32 + col], v0);
        atomicAdd(&agg[(size_t)rv * 64 + wn * 32 + 16 + col], v1);
      }
    }
}

// ---------------------------------------------------------------------------
// Node kernel: per block of 128 nodes,
//   Y = concat(nodes, agg) [128x128] (bf16, K-sliced; agg aliases d_out —
//   each block reads only its own 128 rows, then overwrites them at the end)
//   H = relu(Y @ node_W1 + b1);  y = H @ node_W2 + b2
//   out = nodes + LayerNorm(y) * ln_scale + ln_offset
// ---------------------------------------------------------------------------
__global__ __launch_bounds__(256) void node_kernel(
    const float* __restrict__ nodes, const float* agg,
    const unsigned short* __restrict__ W1f, const unsigned short* __restrict__ W2f,
    const float* __restrict__ b1, const float* __restrict__ b2,
    const float* __restrict__ ln_s, const float* __restrict__ ln_o,
    float* out, int N) {
  __shared__ unsigned short Xs[128 * 40];
  __shared__ unsigned short Ws[4096];
  __shared__ unsigned short Hl[128 * 136];
  __shared__ float Ls1[128][2];
  __shared__ float Ls2[128][2];

  const int tid = threadIdx.x;
  const int n0 = blockIdx.x * 128;
  const int w = tid >> 6, lane = tid & 63;
  const int col = lane & 15, quad = lane >> 4;
  const int wm = w & 1, wn = w >> 1;

  floatx4 z4 = {0.f, 0.f, 0.f, 0.f};
  floatx4 acc1[4][4];
#pragma unroll
  for (int mt = 0; mt < 4; ++mt)
#pragma unroll
    for (int nt = 0; nt < 4; ++nt) acc1[mt][nt] = z4;

  for (int ks = 0; ks < 4; ++ks) {
    __syncthreads();
    for (int t = tid; t < 1024; t += 256) {
      int e = t >> 3, c = t & 7;
      int gi = n0 + e;
      float4 v;
      if (gi < N) {
        const float* src = ((ks < 2) ? nodes : agg) + (size_t)gi * 64 + (ks & 1) * 32 + c * 4;
        v = *(const float4*)src;
      } else {
        v = make_float4(0.f, 0.f, 0.f, 0.f);
      }
      u16x4 h;
      h.x = f2bf(v.x); h.y = f2bf(v.y); h.z = f2bf(v.z); h.w = f2bf(v.w);
      *(u16x4*)&Xs[e * 40 + c * 4] = h;
    }
    *(u16x8*)&Ws[tid * 8] = *(const u16x8*)&W1f[ks * 4096 + tid * 8];
    *(u16x8*)&Ws[(tid + 256) * 8] = *(const u16x8*)&W1f[ks * 4096 + (tid + 256) * 8];
    __syncthreads();

    bf16x8 a[4], b[4];
#pragma unroll
    for (int mt = 0; mt < 4; ++mt)
      a[mt] = *(const bf16x8*)&Xs[(wm * 64 + mt * 16 + col) * 40 + quad * 8];
#pragma unroll
    for (int nt = 0; nt < 4; ++nt)
      b[nt] = *(const bf16x8*)&Ws[(quad * 128 + wn * 64 + nt * 16 + col) * 8];
#pragma unroll
    for (int mt = 0; mt < 4; ++mt)
#pragma unroll
      for (int nt = 0; nt < 4; ++nt)
        acc1[mt][nt] = __builtin_amdgcn_mfma_f32_16x16x32_bf16(a[mt], b[nt], acc1[mt][nt], 0, 0, 0);
  }

#pragma unroll
  for (int nt = 0; nt < 4; ++nt) {
    float bias = b1[wn * 64 + nt * 16 + col];
#pragma unroll
    for (int mt = 0; mt < 4; ++mt)
#pragma unroll
      for (int r = 0; r < 4; ++r) {
        float v = acc1[mt][nt][r] + bias;
        v = v > 0.f ? v : 0.f;
        Hl[(wm * 64 + mt * 16 + quad * 4 + r) * 136 + wn * 64 + nt * 16 + col] = f2bf(v);
      }
  }

  floatx4 acc2[4][2];
#pragma unroll
  for (int mt = 0; mt < 4; ++mt) { acc2[mt][0] = z4; acc2[mt][1] = z4; }

  for (int ks = 0; ks < 4; ++ks) {
    __syncthreads();
    *(u16x8*)&Ws[tid * 8] = *(const u16x8*)&W2f[ks * 2048 + tid * 8];
    __syncthreads();
    bf16x8 a[4], b[2];
#pragma unroll
    for (int mt = 0; mt < 4; ++mt)
      a[mt] = *(const bf16x8*)&Hl[(wm * 64 + mt * 16 + col) * 136 + ks * 32 + quad * 8];
#pragma unroll
    for (int nt = 0; nt < 2; ++nt)
      b[nt] = *(const bf16x8*)&Ws[(quad * 64 + wn * 32 + nt * 16 + col) * 8];
#pragma unroll
    for (int mt = 0; mt < 4; ++mt)
#pragma unroll
      for (int nt = 0; nt < 2; ++nt)
        acc2[mt][nt] = __builtin_amdgcn_mfma_f32_16x16x32_bf16(a[mt], b[nt], acc2[mt][nt], 0, 0, 0);
  }

  // bias
  float y[4][2][4];
  float bs0 = b2[wn * 32 + col];
  float bs1 = b2[wn * 32 + 16 + col];
#pragma unroll
  for (int mt = 0; mt < 4; ++mt)
#pragma unroll
    for (int r = 0; r < 4; ++r) {
      y[mt][0][r] = acc2[mt][0][r] + bs0;
      y[mt][1][r] = acc2[mt][1][r] + bs1;
    }

  // LayerNorm partial sums: reduce 32 cols of this wave across 16-lane quad,
  // combine the two column-halves (wn=0/1) through LDS.
#pragma unroll
  for (int mt = 0; mt < 4; ++mt)
#pragma unroll
    for (int r = 0; r < 4; ++r) {
      float p1 = y[mt][0][r] + y[mt][1][r];
      float p2 = y[mt][0][r] * y[mt][0][r] + y[mt][1][r] * y[mt][1][r];
#pragma unroll
      for (int m = 1; m <= 8; m <<= 1) {
        p1 += __shfl_xor(p1, m);
        p2 += __shfl_xor(p2, m);
      }
      if (col == 0) {
        int row = wm * 64 + mt * 16 + quad * 4 + r;
        Ls1[row][wn] = p1;
        Ls2[row][wn] = p2;
      }
    }
  __syncthreads();

  float lsv0 = ln_s[wn * 32 + col],      lsv1 = ln_s[wn * 32 + 16 + col];
  float lov0 = ln_o[wn * 32 + col],      lov1 = ln_o[wn * 32 + 16 + col];
#pragma unroll
  for (int mt = 0; mt < 4; ++mt)
#pragma unroll
    for (int r = 0; r < 4; ++r) {
      int row = wm * 64 + mt * 16 + quad * 4 + r;
      int gi = n0 + row;
      float s1 = Ls1[row][0] + Ls1[row][1];
      float s2 = Ls2[row][0] + Ls2[row][1];
      float mean = s1 * (1.f / 64.f);
      float var = s2 * (1.f / 64.f) - mean * mean;
      float rstd = rsqrtf(var + 1e-5f);
      if (gi < N) {
        int j0 = wn * 32 + col;
        float o0 = (y[mt][0][r] - mean) * rstd * lsv0 + lov0 + nodes[(size_t)gi * 64 + j0];
        float o1 = (y[mt][1][r] - mean) * rstd * lsv1 + lov1 + nodes[(size_t)gi * 64 + j0 + 16];
        out[(size_t)gi * 64 + j0] = o0;
        out[(size_t)gi * 64 + j0 + 16] = o1;
      }
    }
}

extern "C" void kernel_launch(void* const* d_in, const int* in_sizes, int n_in,
                              void* d_out, int out_size, void* d_ws, size_t ws_size,
                              hipStream_t stream) {
  const float* nodes     = (const float*)d_in[0];
  const float* edges     = (const float*)d_in[1];
  const int*   senders   = (const int*)d_in[2];
  const int*   receivers = (const int*)d_in[3];
  const float* msg_W1    = (const float*)d_in[4];
  const float* msg_b1    = (const float*)d_in[5];
  const float* msg_W2    = (const float*)d_in[6];
  const float* msg_b2    = (const float*)d_in[7];
  const float* node_W1   = (const float*)d_in[8];
  const float* node_b1   = (const float*)d_in[9];
  const float* node_W2   = (const float*)d_in[10];
  const float* node_b2   = (const float*)d_in[11];
  const float* ln_scale  = (const float*)d_in[12];
  const float* ln_offset = (const float*)d_in[13];

  const int N = in_sizes[0] / 64;
  const int E = in_sizes[2];

  // Workspace: packed bf16 weights only (~115 KB).
  unsigned short* W1f  = (unsigned short*)d_ws;  // 24576
  unsigned short* W2f  = W1f + 24576;            // 8192
  unsigned short* NW1f = W2f + 8192;             // 16384
  unsigned short* NW2f = NW1f + 16384;           // 8192

  // d_out doubles as the fp32 aggregation buffer (N*64 floats, exactly out_size).
  float* agg = (float*)d_out;

  hipMemsetAsync(d_out, 0, (size_t)out_size * sizeof(float), stream);
  prep_weights<<<224, 256, 0, stream>>>(msg_W1, msg_W2, node_W1, node_W2, W1f, W2f, NW1f, NW2f);
  edge_kernel<<<(E + 127) / 128, 256, 0, stream>>>(nodes, edges, senders, receivers,
                                                   W1f, W2f, msg_b1, msg_b2, agg, E);
  node_kernel<<<(N + 127) / 128, 256, 0, stream>>>(nodes, agg, NW1f, NW2f,
                                                   node_b1, node_b2, ln_scale, ln_offset,
                                                   (float*)d_out, N);
}

// Round 2
// 1010.606 us; speedup vs baseline: 1.1659x; 1.1659x over previous
//
#include <hip/hip_runtime.h>

typedef short bf16x8 __attribute__((ext_vector_type(8)));
typedef float floatx4 __attribute__((ext_vector_type(4)));
typedef unsigned short u16x4 __attribute__((ext_vector_type(4)));
typedef unsigned short u16x8 __attribute__((ext_vector_type(8)));

__device__ __forceinline__ unsigned short f2bf(float f) {
  union { float f; unsigned int u; } v;
  v.f = f;
  unsigned int u = v.u + (0x7FFFu + ((v.u >> 16) & 1u));  // RNE
  return (unsigned short)(u >> 16);
}

__device__ __forceinline__ bf16x8 pack8(float4 a, float4 b) {
  u16x8 h;
  h[0] = f2bf(a.x); h[1] = f2bf(a.y); h[2] = f2bf(a.z); h[3] = f2bf(a.w);
  h[4] = f2bf(b.x); h[5] = f2bf(b.y); h[6] = f2bf(b.z); h[7] = f2bf(b.w);
  union { u16x8 u; bf16x8 s; } cv; cv.u = h; return cv.s;
}

// ---------------------------------------------------------------------------
// Pack weights to bf16 fragment layout Wf[g][n][j] = W[g*8+j][n] (g=k/8,j=k%8)
// so a lane's B-fragment (8 bf16 along k) is 16 contiguous bytes.
// ---------------------------------------------------------------------------
__global__ __launch_bounds__(256) void prep_weights(
    const float* __restrict__ mW1, const float* __restrict__ mW2,
    const float* __restrict__ nW1, const float* __restrict__ nW2,
    unsigned short* __restrict__ W1f, unsigned short* __restrict__ W2f,
    unsigned short* __restrict__ NW1f, unsigned short* __restrict__ NW2f) {
  int idx = blockIdx.x * 256 + threadIdx.x;
  if (idx < 24576) {
    int j = idx & 7, n = (idx >> 3) & 127, g = idx >> 10;
    W1f[idx] = f2bf(mW1[(g * 8 + j) * 128 + n]);
  } else if (idx < 32768) {
    int t = idx - 24576;
    int j = t & 7, n = (t >> 3) & 63, g = t >> 9;
    W2f[t] = f2bf(mW2[(g * 8 + j) * 64 + n]);
  } else if (idx < 49152) {
    int t = idx - 32768;
    int j = t & 7, n = (t >> 3) & 127, g = t >> 10;
    NW1f[t] = f2bf(nW1[(g * 8 + j) * 128 + n]);
  } else if (idx < 57344) {
    int t = idx - 49152;
    int j = t & 7, n = (t >> 3) & 63, g = t >> 9;
    NW2f[t] = f2bf(nW2[(g * 8 + j) * 64 + n]);
  }
}

// nodes fp32 -> bf16 once (removes per-edge converts; halves gather bytes)
__global__ __launch_bounds__(256) void conv_nodes(
    const float* __restrict__ nodes, unsigned short* __restrict__ nodes_bf, int total4) {
  int i = (blockIdx.x * 256 + threadIdx.x) * 4;
  if (i < total4) {
    float4 v = *(const float4*)(nodes + i);
    u16x4 h; h[0] = f2bf(v.x); h[1] = f2bf(v.y); h[2] = f2bf(v.z); h[3] = f2bf(v.w);
    *(u16x4*)(nodes_bf + i) = h;
  }
}

// ---------------------------------------------------------------------------
// Edge kernel, barrier-minimal: A- and B-fragments load DIRECTLY from global
// into registers (16 B/lane, used once; weights L2-hot). Only LDS use is the
// C-layout -> A-layout transform of H (one __syncthreads in the whole kernel).
// ---------------------------------------------------------------------------
__global__ __launch_bounds__(256, 3) void edge_kernel(
    const float* __restrict__ edges, const unsigned short* __restrict__ nodes_bf,
    const int* __restrict__ senders, const int* __restrict__ receivers,
    const unsigned short* __restrict__ W1f, const unsigned short* __restrict__ W2f,
    const float* __restrict__ b1, const float* __restrict__ b2,
    float* agg, int E) {
  __shared__ unsigned short Hl[128 * 136];  // hidden, pad 128->136

  const int tid = threadIdx.x;
  const int e0 = blockIdx.x * 128;
  const int w = tid >> 6, lane = tid & 63;
  const int col = lane & 15, quad = lane >> 4;
  const int wm = w & 1, wn = w >> 1;

  // gather indices for this lane's A-rows (row = wm*64 + mt*16 + col)
  int srow[4], sndi[4], rcvi[4];
#pragma unroll
  for (int mt = 0; mt < 4; ++mt) {
    int r = e0 + wm * 64 + mt * 16 + col;
    srow[mt] = r < E ? r : E - 1;
  }
#pragma unroll
  for (int mt = 0; mt < 4; ++mt) { sndi[mt] = senders[srow[mt]]; rcvi[mt] = receivers[srow[mt]]; }

  floatx4 z4 = {0.f, 0.f, 0.f, 0.f};
  floatx4 acc1[4][4];
#pragma unroll
  for (int mt = 0; mt < 4; ++mt)
#pragma unroll
    for (int nt = 0; nt < 4; ++nt) acc1[mt][nt] = z4;

  // GEMM1, K=192: slices 0,1 = sender feats; 2,3 = receiver feats; 4,5 = edge feats
#pragma unroll
  for (int ks = 0; ks < 4; ++ks) {
    bf16x8 a[4], b[4];
#pragma unroll
    for (int mt = 0; mt < 4; ++mt) {
      int nd = (ks < 2) ? sndi[mt] : rcvi[mt];
      a[mt] = *(const bf16x8*)&nodes_bf[(size_t)nd * 64 + (ks & 1) * 32 + quad * 8];
    }
#pragma unroll
    for (int nt = 0; nt < 4; ++nt)
      b[nt] = *(const bf16x8*)&W1f[ks * 4096 + quad * 1024 + (wn * 64 + nt * 16 + col) * 8];
#pragma unroll
    for (int mt = 0; mt < 4; ++mt)
#pragma unroll
      for (int nt = 0; nt < 4; ++nt)
        acc1[mt][nt] = __builtin_amdgcn_mfma_f32_16x16x32_bf16(a[mt], b[nt], acc1[mt][nt], 0, 0, 0);
  }
#pragma unroll
  for (int ks = 4; ks < 6; ++ks) {
    bf16x8 a[4], b[4];
#pragma unroll
    for (int mt = 0; mt < 4; ++mt) {
      const float* p = edges + (size_t)srow[mt] * 64 + (ks - 4) * 32 + quad * 8;
      float4 v0 = *(const float4*)p;
      float4 v1 = *(const float4*)(p + 4);
      a[mt] = pack8(v0, v1);
    }
#pragma unroll
    for (int nt = 0; nt < 4; ++nt)
      b[nt] = *(const bf16x8*)&W1f[ks * 4096 + quad * 1024 + (wn * 64 + nt * 16 + col) * 8];
#pragma unroll
    for (int mt = 0; mt < 4; ++mt)
#pragma unroll
      for (int nt = 0; nt < 4; ++nt)
        acc1[mt][nt] = __builtin_amdgcn_mfma_f32_16x16x32_bf16(a[mt], b[nt], acc1[mt][nt], 0, 0, 0);
  }

  // bias + ReLU -> Hl (bf16), C-layout -> A-layout via LDS
#pragma unroll
  for (int nt = 0; nt < 4; ++nt) {
    float bias = b1[wn * 64 + nt * 16 + col];
#pragma unroll
    for (int mt = 0; mt < 4; ++mt)
#pragma unroll
      for (int r = 0; r < 4; ++r) {
        float v = acc1[mt][nt][r] + bias;
        v = v > 0.f ? v : 0.f;
        Hl[(wm * 64 + mt * 16 + quad * 4 + r) * 136 + wn * 64 + nt * 16 + col] = f2bf(v);
      }
  }
  __syncthreads();  // the only barrier

  floatx4 acc2[4][2];
#pragma unroll
  for (int mt = 0; mt < 4; ++mt) { acc2[mt][0] = z4; acc2[mt][1] = z4; }

  // GEMM2, K=128: A from LDS, B direct from global (L2-hot)
#pragma unroll
  for (int ks = 0; ks < 4; ++ks) {
    bf16x8 a[4], b[2];
#pragma unroll
    for (int mt = 0; mt < 4; ++mt)
      a[mt] = *(const bf16x8*)&Hl[(wm * 64 + mt * 16 + col) * 136 + ks * 32 + quad * 8];
#pragma unroll
    for (int nt = 0; nt < 2; ++nt)
      b[nt] = *(const bf16x8*)&W2f[ks * 2048 + quad * 512 + (wn * 32 + nt * 16 + col) * 8];
#pragma unroll
    for (int mt = 0; mt < 4; ++mt)
#pragma unroll
      for (int nt = 0; nt < 2; ++nt)
        acc2[mt][nt] = __builtin_amdgcn_mfma_f32_16x16x32_bf16(a[mt], b[nt], acc2[mt][nt], 0, 0, 0);
  }

  float bs0 = b2[wn * 32 + col];
  float bs1 = b2[wn * 32 + 16 + col];
#pragma unroll
  for (int mt = 0; mt < 4; ++mt)
#pragma unroll
    for (int r = 0; r < 4; ++r) {
      int er = e0 + wm * 64 + mt * 16 + quad * 4 + r;
      if (er < E) {
        int rv = receivers[er];
        float v0 = acc2[mt][0][r] + bs0; v0 = v0 > 0.f ? v0 : 0.f;
        float v1 = acc2[mt][1][r] + bs1; v1 = v1 > 0.f ? v1 : 0.f;
        atomicAdd(&agg[(size_t)rv * 64 + wn * 32 + col], v0);
        atomicAdd(&agg[(size_t)rv * 64 + wn * 32 + 16 + col], v1);
      }
    }
}

// ---------------------------------------------------------------------------
// Node kernel, same barrier-minimal structure.
//   Y = concat(nodes, agg); H = relu(Y@W1+b1); y = H@W2+b2
//   out = nodes + LN(y)*scale + offset   (agg aliases d_out; block-local RAW)
// ---------------------------------------------------------------------------
__global__ __launch_bounds__(256, 3) void node_kernel(
    const float* __restrict__ nodes, const unsigned short* __restrict__ nodes_bf,
    const float* agg,
    const unsigned short* __restrict__ W1f, const unsigned short* __restrict__ W2f,
    const float* __restrict__ b1, const float* __restrict__ b2,
    const float* __restrict__ ln_s, const float* __restrict__ ln_o,
    float* out, int N) {
  __shared__ unsigned short Hl[128 * 136];
  __shared__ float Ls1[128][2];
  __shared__ float Ls2[128][2];

  const int tid = threadIdx.x;
  const int n0 = blockIdx.x * 128;
  const int w = tid >> 6, lane = tid & 63;
  const int col = lane & 15, quad = lane >> 4;
  const int wm = w & 1, wn = w >> 1;

  int arow[4];
#pragma unroll
  for (int mt = 0; mt < 4; ++mt) {
    int r = n0 + wm * 64 + mt * 16 + col;
    arow[mt] = r < N ? r : N - 1;
  }

  floatx4 z4 = {0.f, 0.f, 0.f, 0.f};
  floatx4 acc1[4][4];
#pragma unroll
  for (int mt = 0; mt < 4; ++mt)
#pragma unroll
    for (int nt = 0; nt < 4; ++nt) acc1[mt][nt] = z4;

  // GEMM1, K=128: slices 0,1 = node feats (bf16); 2,3 = agg (fp32)
#pragma unroll
  for (int ks = 0; ks < 2; ++ks) {
    bf16x8 a[4], b[4];
#pragma unroll
    for (int mt = 0; mt < 4; ++mt)
      a[mt] = *(const bf16x8*)&nodes_bf[(size_t)arow[mt] * 64 + ks * 32 + quad * 8];
#pragma unroll
    for (int nt = 0; nt < 4; ++nt)
      b[nt] = *(const bf16x8*)&W1f[ks * 4096 + quad * 1024 + (wn * 64 + nt * 16 + col) * 8];
#pragma unroll
    for (int mt = 0; mt < 4; ++mt)
#pragma unroll
      for (int nt = 0; nt < 4; ++nt)
        acc1[mt][nt] = __builtin_amdgcn_mfma_f32_16x16x32_bf16(a[mt], b[nt], acc1[mt][nt], 0, 0, 0);
  }
#pragma unroll
  for (int ks = 2; ks < 4; ++ks) {
    bf16x8 a[4], b[4];
#pragma unroll
    for (int mt = 0; mt < 4; ++mt) {
      const float* p = agg + (size_t)arow[mt] * 64 + (ks - 2) * 32 + quad * 8;
      float4 v0 = *(const float4*)p;
      float4 v1 = *(const float4*)(p + 4);
      a[mt] = pack8(v0, v1);
    }
#pragma unroll
    for (int nt = 0; nt < 4; ++nt)
      b[nt] = *(const bf16x8*)&W1f[ks * 4096 + quad * 1024 + (wn * 64 + nt * 16 + col) * 8];
#pragma unroll
    for (int mt = 0; mt < 4; ++mt)
#pragma unroll
      for (int nt = 0; nt < 4; ++nt)
        acc1[mt][nt] = __builtin_amdgcn_mfma_f32_16x16x32_bf16(a[mt], b[nt], acc1[mt][nt], 0, 0, 0);
  }

#pragma unroll
  for (int nt = 0; nt < 4; ++nt) {
    float bias = b1[wn * 64 + nt * 16 + col];
#pragma unroll
    for (int mt = 0; mt < 4; ++mt)
#pragma unroll
      for (int r = 0; r < 4; ++r) {
        float v = acc1[mt][nt][r] + bias;
        v = v > 0.f ? v : 0.f;
        Hl[(wm * 64 + mt * 16 + quad * 4 + r) * 136 + wn * 64 + nt * 16 + col] = f2bf(v);
      }
  }
  __syncthreads();

  floatx4 acc2[4][2];
#pragma unroll
  for (int mt = 0; mt < 4; ++mt) { acc2[mt][0] = z4; acc2[mt][1] = z4; }

#pragma unroll
  for (int ks = 0; ks < 4; ++ks) {
    bf16x8 a[4], b[2];
#pragma unroll
    for (int mt = 0; mt < 4; ++mt)
      a[mt] = *(const bf16x8*)&Hl[(wm * 64 + mt * 16 + col) * 136 + ks * 32 + quad * 8];
#pragma unroll
    for (int nt = 0; nt < 2; ++nt)
      b[nt] = *(const bf16x8*)&W2f[ks * 2048 + quad * 512 + (wn * 32 + nt * 16 + col) * 8];
#pragma unroll
    for (int mt = 0; mt < 4; ++mt)
#pragma unroll
      for (int nt = 0; nt < 2; ++nt)
        acc2[mt][nt] = __builtin_amdgcn_mfma_f32_16x16x32_bf16(a[mt], b[nt], acc2[mt][nt], 0, 0, 0);
  }

  // bias
  float y[4][2][4];
  float bs0 = b2[wn * 32 + col];
  float bs1 = b2[wn * 32 + 16 + col];
#pragma unroll
  for (int mt = 0; mt < 4; ++mt)
#pragma unroll
    for (int r = 0; r < 4; ++r) {
      y[mt][0][r] = acc2[mt][0][r] + bs0;
      y[mt][1][r] = acc2[mt][1][r] + bs1;
    }

  // LayerNorm: reduce this wave's 32 cols across the 16-lane quad,
  // combine the two column-halves (wn=0/1) through LDS.
#pragma unroll
  for (int mt = 0; mt < 4; ++mt)
#pragma unroll
    for (int r = 0; r < 4; ++r) {
      float p1 = y[mt][0][r] + y[mt][1][r];
      float p2 = y[mt][0][r] * y[mt][0][r] + y[mt][1][r] * y[mt][1][r];
#pragma unroll
      for (int m = 1; m <= 8; m <<= 1) {
        p1 += __shfl_xor(p1, m);
        p2 += __shfl_xor(p2, m);
      }
      if (col == 0) {
        int row = wm * 64 + mt * 16 + quad * 4 + r;
        Ls1[row][wn] = p1;
        Ls2[row][wn] = p2;
      }
    }
  __syncthreads();

  float lsv0 = ln_s[wn * 32 + col], lsv1 = ln_s[wn * 32 + 16 + col];
  float lov0 = ln_o[wn * 32 + col], lov1 = ln_o[wn * 32 + 16 + col];
#pragma unroll
  for (int mt = 0; mt < 4; ++mt)
#pragma unroll
    for (int r = 0; r < 4; ++r) {
      int row = wm * 64 + mt * 16 + quad * 4 + r;
      int gi = n0 + row;
      float s1 = Ls1[row][0] + Ls1[row][1];
      float s2 = Ls2[row][0] + Ls2[row][1];
      float mean = s1 * (1.f / 64.f);
      float var = s2 * (1.f / 64.f) - mean * mean;
      float rstd = rsqrtf(var + 1e-5f);
      if (gi < N) {
        int j0 = wn * 32 + col;
        float o0 = (y[mt][0][r] - mean) * rstd * lsv0 + lov0 + nodes[(size_t)gi * 64 + j0];
        float o1 = (y[mt][1][r] - mean) * rstd * lsv1 + lov1 + nodes[(size_t)gi * 64 + j0 + 16];
        out[(size_t)gi * 64 + j0] = o0;
        out[(size_t)gi * 64 + j0 + 16] = o1;
      }
    }
}

extern "C" void kernel_launch(void* const* d_in, const int* in_sizes, int n_in,
                              void* d_out, int out_size, void* d_ws, size_t ws_size,
                              hipStream_t stream) {
  const float* nodes     = (const float*)d_in[0];
  const float* edges     = (const float*)d_in[1];
  const int*   senders   = (const int*)d_in[2];
  const int*   receivers = (const int*)d_in[3];
  const float* msg_W1    = (const float*)d_in[4];
  const float* msg_b1    = (const float*)d_in[5];
  const float* msg_W2    = (const float*)d_in[6];
  const float* msg_b2    = (const float*)d_in[7];
  const float* node_W1   = (const float*)d_in[8];
  const float* node_b1   = (const float*)d_in[9];
  const float* node_W2   = (const float*)d_in[10];
  const float* node_b2   = (const float*)d_in[11];
  const float* ln_scale  = (const float*)d_in[12];
  const float* ln_offset = (const float*)d_in[13];

  const int N = in_sizes[0] / 64;
  const int E = in_sizes[2];

  // Workspace: packed bf16 weights (114 KB) + bf16 nodes (12.8 MB).
  unsigned short* W1f  = (unsigned short*)d_ws;   // 24576
  unsigned short* W2f  = W1f + 24576;             // 8192
  unsigned short* NW1f = W2f + 8192;              // 16384
  unsigned short* NW2f = NW1f + 16384;            // 8192
  unsigned short* nodes_bf = NW2f + 8192;         // N*64

  float* agg = (float*)d_out;  // fp32 aggregation in-place in d_out

  hipMemsetAsync(d_out, 0, (size_t)out_size * sizeof(float), stream);
  prep_weights<<<224, 256, 0, stream>>>(msg_W1, msg_W2, node_W1, node_W2, W1f, W2f, NW1f, NW2f);
  conv_nodes<<<(N * 64 + 1023) / 1024, 256, 0, stream>>>(nodes, nodes_bf, N * 64);
  edge_kernel<<<(E + 127) / 128, 256, 0, stream>>>(edges, nodes_bf, senders, receivers,
                                                   W1f, W2f, msg_b1, msg_b2, agg, E);
  node_kernel<<<(N + 127) / 128, 256, 0, stream>>>(nodes, nodes_bf, agg, NW1f, NW2f,
                                                   node_b1, node_b2, ln_scale, ln_offset,
                                                   (float*)d_out, N);
}